// Round 1
// baseline (221.966 us; speedup 1.0000x reference)
//
#include <hip/hip_runtime.h>
#include <hip/hip_bf16.h>
#include <cstddef>

#define N_ROWS 8192
#define M_ROWS 8192
#define D_IN   64
#define H_DIM  32
#define T_OUT  8

#define TPB2   256
#define RPT    2      // i-rows per thread in pair kernel
#define JCHUNK 256    // j-columns per block (M split into 32 chunks)
#define NSPLIT (M_ROWS / JCHUNK)

// ---------------------------------------------------------------------------
// Kernel 1: features. rows 0..N-1 -> MLP(X), rows N..N+M-1 -> MLP(Y).
// Writes feat[row][32] and norm[row] = ||feat_row||^2.
// ---------------------------------------------------------------------------
__global__ __launch_bounds__(64) void feat_kernel(
    const float* __restrict__ X, const float* __restrict__ Y,
    const float* __restrict__ W1, const float* __restrict__ b1,
    const float* __restrict__ W2, const float* __restrict__ b2,
    const float* __restrict__ W3, const float* __restrict__ b3,
    float* __restrict__ feat, float* __restrict__ norm)
{
    __shared__ float wl[2048 + 1024 + 1024 + 32 + 32 + 32];
    float* w1l = wl;                 // 2048
    float* w2l = w1l + 2048;         // 1024
    float* w3l = w2l + 1024;         // 1024
    float* b1l = w3l + 1024;         // 32
    float* b2l = b1l + 32;           // 32
    float* b3l = b2l + 32;           // 32

    const int tid = threadIdx.x;
    for (int i = tid; i < 2048; i += 64) w1l[i] = W1[i];
    for (int i = tid; i < 1024; i += 64) w2l[i] = W2[i];
    for (int i = tid; i < 1024; i += 64) w3l[i] = W3[i];
    if (tid < 32) { b1l[tid] = b1[tid]; b2l[tid] = b2[tid]; b3l[tid] = b3[tid]; }
    __syncthreads();

    const int row = blockIdx.x * 64 + tid;
    const float* src = (row < N_ROWS) ? (X + (size_t)row * D_IN)
                                      : (Y + (size_t)(row - N_ROWS) * D_IN);

    float x[D_IN];
    {
        const float4* s4 = (const float4*)src;
        #pragma unroll
        for (int c = 0; c < 16; ++c) {
            float4 v = s4[c];
            x[4*c+0] = v.x; x[4*c+1] = v.y; x[4*c+2] = v.z; x[4*c+3] = v.w;
        }
    }

    // Layer 1: h1 = relu(x @ W1 + b1), W1 is [64][32]
    float h1[H_DIM];
    {
        const float4* wq = (const float4*)w1l;
        const float4* bq = (const float4*)b1l;
        for (int q = 0; q < 8; ++q) {
            float4 a = bq[q];
            #pragma unroll 8
            for (int k = 0; k < 64; ++k) {
                float4 w = wq[k*8 + q];
                a.x = fmaf(x[k], w.x, a.x);
                a.y = fmaf(x[k], w.y, a.y);
                a.z = fmaf(x[k], w.z, a.z);
                a.w = fmaf(x[k], w.w, a.w);
            }
            h1[4*q+0] = fmaxf(a.x, 0.f);
            h1[4*q+1] = fmaxf(a.y, 0.f);
            h1[4*q+2] = fmaxf(a.z, 0.f);
            h1[4*q+3] = fmaxf(a.w, 0.f);
        }
    }

    // Layer 2: h2 = relu(h1 @ W2 + b2), W2 is [32][32]
    float h2[H_DIM];
    {
        const float4* wq = (const float4*)w2l;
        const float4* bq = (const float4*)b2l;
        for (int q = 0; q < 8; ++q) {
            float4 a = bq[q];
            #pragma unroll 8
            for (int k = 0; k < 32; ++k) {
                float4 w = wq[k*8 + q];
                a.x = fmaf(h1[k], w.x, a.x);
                a.y = fmaf(h1[k], w.y, a.y);
                a.z = fmaf(h1[k], w.z, a.z);
                a.w = fmaf(h1[k], w.w, a.w);
            }
            h2[4*q+0] = fmaxf(a.x, 0.f);
            h2[4*q+1] = fmaxf(a.y, 0.f);
            h2[4*q+2] = fmaxf(a.z, 0.f);
            h2[4*q+3] = fmaxf(a.w, 0.f);
        }
    }

    // Layer 3: h3 = relu(h2 @ W3 + b3); store + norm
    float nrm = 0.f;
    {
        const float4* wq = (const float4*)w3l;
        const float4* bq = (const float4*)b3l;
        float4* fq = (float4*)(feat + (size_t)row * H_DIM);
        for (int q = 0; q < 8; ++q) {
            float4 a = bq[q];
            #pragma unroll 8
            for (int k = 0; k < 32; ++k) {
                float4 w = wq[k*8 + q];
                a.x = fmaf(h2[k], w.x, a.x);
                a.y = fmaf(h2[k], w.y, a.y);
                a.z = fmaf(h2[k], w.z, a.z);
                a.w = fmaf(h2[k], w.w, a.w);
            }
            a.x = fmaxf(a.x, 0.f); a.y = fmaxf(a.y, 0.f);
            a.z = fmaxf(a.z, 0.f); a.w = fmaxf(a.w, 0.f);
            fq[q] = a;
            nrm = fmaf(a.x, a.x, nrm);
            nrm = fmaf(a.y, a.y, nrm);
            nrm = fmaf(a.z, a.z, nrm);
            nrm = fmaf(a.w, a.w, nrm);
        }
    }
    norm[row] = nrm;
}

// ---------------------------------------------------------------------------
// Kernel 2: fused pair kernel. Each block: 512 i-rows x one 256-j chunk.
// Accumulates sum_j w_ij * Yt[j][:] and sum_j w_ij.
// ---------------------------------------------------------------------------
template <bool USE_ATOMIC>
__global__ __launch_bounds__(TPB2) void pair_kernel(
    const float* __restrict__ feat, const float* __restrict__ norm,
    const float* __restrict__ Yt,
    float* __restrict__ pout, float* __restrict__ psum,
    float* __restrict__ acc,  float* __restrict__ wsum)
{
    const int tid = threadIdx.x;
    const int i0 = blockIdx.x * (TPB2 * RPT) + tid;
    const int i1 = i0 + TPB2;
    const int jbase = blockIdx.y * JCHUNK;

    float4 q0[8], q1[8];
    {
        const float4* p0 = (const float4*)(feat + (size_t)i0 * H_DIM);
        const float4* p1 = (const float4*)(feat + (size_t)i1 * H_DIM);
        #pragma unroll
        for (int c = 0; c < 8; ++c) { q0[c] = p0[c]; q1[c] = p1[c]; }
    }
    const float qq0 = norm[i0];
    const float qq1 = norm[i1];

    const float* yfbase = feat + (size_t)(N_ROWS + jbase) * H_DIM;
    const float* kkbase = norm + N_ROWS + jbase;
    const float* ytbase = Yt + (size_t)jbase * T_OUT;

    float a0[T_OUT], a1[T_OUT];
    #pragma unroll
    for (int t = 0; t < T_OUT; ++t) { a0[t] = 0.f; a1[t] = 0.f; }
    float s0 = 0.f, s1 = 0.f;

    for (int j = 0; j < JCHUNK; ++j) {
        const float4* y4 = (const float4*)(yfbase + j * H_DIM);
        float d0 = 0.f, d1 = 0.f;
        #pragma unroll
        for (int c = 0; c < 8; ++c) {
            float4 y = y4[c];
            d0 = fmaf(q0[c].x, y.x, d0); d0 = fmaf(q0[c].y, y.y, d0);
            d0 = fmaf(q0[c].z, y.z, d0); d0 = fmaf(q0[c].w, y.w, d0);
            d1 = fmaf(q1[c].x, y.x, d1); d1 = fmaf(q1[c].y, y.y, d1);
            d1 = fmaf(q1[c].z, y.z, d1); d1 = fmaf(q1[c].w, y.w, d1);
        }
        const float kkj = kkbase[j];
        float sq0 = fmaxf(qq0 + kkj - 2.f * d0, 0.f);
        float sq1 = fmaxf(qq1 + kkj - 2.f * d1, 0.f);
        float w0 = __expf(-0.5f * sq0);
        float w1 = __expf(-0.5f * sq1);

        const float4* t4 = (const float4*)(ytbase + j * T_OUT);
        float4 ta = t4[0], tb = t4[1];
        a0[0] = fmaf(w0, ta.x, a0[0]); a0[1] = fmaf(w0, ta.y, a0[1]);
        a0[2] = fmaf(w0, ta.z, a0[2]); a0[3] = fmaf(w0, ta.w, a0[3]);
        a0[4] = fmaf(w0, tb.x, a0[4]); a0[5] = fmaf(w0, tb.y, a0[5]);
        a0[6] = fmaf(w0, tb.z, a0[6]); a0[7] = fmaf(w0, tb.w, a0[7]);
        a1[0] = fmaf(w1, ta.x, a1[0]); a1[1] = fmaf(w1, ta.y, a1[1]);
        a1[2] = fmaf(w1, ta.z, a1[2]); a1[3] = fmaf(w1, ta.w, a1[3]);
        a1[4] = fmaf(w1, tb.x, a1[4]); a1[5] = fmaf(w1, tb.y, a1[5]);
        a1[6] = fmaf(w1, tb.z, a1[6]); a1[7] = fmaf(w1, tb.w, a1[7]);
        s0 += w0; s1 += w1;
    }

    if (USE_ATOMIC) {
        #pragma unroll
        for (int t = 0; t < T_OUT; ++t) {
            atomicAdd(&acc[(size_t)i0 * T_OUT + t], a0[t]);
            atomicAdd(&acc[(size_t)i1 * T_OUT + t], a1[t]);
        }
        atomicAdd(&wsum[i0], s0);
        atomicAdd(&wsum[i1], s1);
    } else {
        const int s = blockIdx.y;
        float4* o0 = (float4*)(pout + ((size_t)s * N_ROWS + i0) * T_OUT);
        float4* o1 = (float4*)(pout + ((size_t)s * N_ROWS + i1) * T_OUT);
        o0[0] = make_float4(a0[0], a0[1], a0[2], a0[3]);
        o0[1] = make_float4(a0[4], a0[5], a0[6], a0[7]);
        o1[0] = make_float4(a1[0], a1[1], a1[2], a1[3]);
        o1[1] = make_float4(a1[4], a1[5], a1[6], a1[7]);
        psum[(size_t)s * N_ROWS + i0] = s0;
        psum[(size_t)s * N_ROWS + i1] = s1;
    }
}

// ---------------------------------------------------------------------------
// Kernel 3a: reduce partials across the NSPLIT chunks and normalize.
// ---------------------------------------------------------------------------
__global__ __launch_bounds__(256) void reduce_kernel(
    const float* __restrict__ pout, const float* __restrict__ psum,
    float* __restrict__ out)
{
    const int id = blockIdx.x * 256 + threadIdx.x;   // 0..65535
    const int i = id >> 3;
    const int t = id & 7;
    float sv = 0.f, sw = 0.f;
    #pragma unroll
    for (int s = 0; s < NSPLIT; ++s) {
        sv += pout[((size_t)s * N_ROWS + i) * T_OUT + t];
        sw += psum[(size_t)s * N_ROWS + i];
    }
    out[id] = sv / sw;
}

// Kernel 3b: normalize for the atomic path.
__global__ __launch_bounds__(256) void norm_kernel(
    const float* __restrict__ acc, const float* __restrict__ wsum,
    float* __restrict__ out)
{
    const int id = blockIdx.x * 256 + threadIdx.x;
    out[id] = acc[id] / wsum[id >> 3];
}

// ---------------------------------------------------------------------------
extern "C" void kernel_launch(void* const* d_in, const int* in_sizes, int n_in,
                              void* d_out, int out_size, void* d_ws, size_t ws_size,
                              hipStream_t stream)
{
    const float* X  = (const float*)d_in[0];
    const float* Y  = (const float*)d_in[1];
    const float* Yt = (const float*)d_in[2];
    const float* W1 = (const float*)d_in[3];
    const float* b1 = (const float*)d_in[4];
    const float* W2 = (const float*)d_in[5];
    const float* b2 = (const float*)d_in[6];
    const float* W3 = (const float*)d_in[7];
    const float* b3 = (const float*)d_in[8];
    float* out = (float*)d_out;

    float* ws   = (float*)d_ws;
    float* feat = ws;                                  // 16384*32 = 524288 floats
    float* norm = feat + (size_t)(N_ROWS + M_ROWS) * H_DIM;   // 16384 floats
    float* rest = norm + (N_ROWS + M_ROWS);

    const size_t pout_elems = (size_t)NSPLIT * N_ROWS * T_OUT;  // 2 M floats
    const size_t psum_elems = (size_t)NSPLIT * N_ROWS;          // 256 K floats
    const size_t base_elems = (size_t)(N_ROWS + M_ROWS) * (H_DIM + 1);
    const size_t need_partial = (base_elems + pout_elems + psum_elems) * sizeof(float);

    feat_kernel<<<(N_ROWS + M_ROWS) / 64, 64, 0, stream>>>(
        X, Y, W1, b1, W2, b2, W3, b3, feat, norm);

    dim3 grid2(N_ROWS / (TPB2 * RPT), NSPLIT);

    if (ws_size >= need_partial) {
        float* pout = rest;
        float* psum = rest + pout_elems;
        pair_kernel<false><<<grid2, TPB2, 0, stream>>>(
            feat, norm, Yt, pout, psum, nullptr, nullptr);
        reduce_kernel<<<(N_ROWS * T_OUT) / 256, 256, 0, stream>>>(pout, psum, out);
    } else {
        float* acc  = rest;                         // 65536 floats
        float* wsum = rest + (size_t)N_ROWS * T_OUT; // 8192 floats
        hipMemsetAsync(rest, 0, (size_t)(N_ROWS * T_OUT + N_ROWS) * sizeof(float), stream);
        pair_kernel<true><<<grid2, TPB2, 0, stream>>>(
            feat, norm, Yt, nullptr, nullptr, acc, wsum);
        norm_kernel<<<(N_ROWS * T_OUT) / 256, 256, 0, stream>>>(acc, wsum, out);
    }
}

// Round 4
// 143.076 us; speedup vs baseline: 1.5514x; 1.5514x over previous
//
#include <hip/hip_runtime.h>
#include <hip/hip_bf16.h>
#include <cstddef>

#define N_ROWS 8192
#define M_ROWS 8192
#define D_IN   64
#define H_DIM  32
#define T_OUT  8

#define NSPLIT   16          // j-splits (blockIdx.y)
#define JSLICE   (M_ROWS / NSPLIT)   // 512 cols per block
#define JTILE    32
#define NTILES   (JSLICE / JTILE)    // 16 j-tiles per block
#define LOG2E    1.4426950408889634f
#define NHALF_SC (-0.72134752044448169f)   // -0.5*log2(e)
#define PSTRIDE  34          // padded dword stride of packed P rows

typedef _Float16 half8  __attribute__((ext_vector_type(8)));
typedef __fp16   fp16x2 __attribute__((ext_vector_type(2)));
typedef float    f32x4  __attribute__((ext_vector_type(4)));
typedef float    f32x16 __attribute__((ext_vector_type(16)));

__device__ __forceinline__ half8 ld_h8(const _Float16* p) {
    return *(const half8*)p;
}

// ---------------------------------------------------------------------------
// Kernel 1: features. rows 0..N-1 -> MLP(X) (scaled by log2e), rows N..N+M-1
// -> MLP(Y) (unscaled). Emits fp16 hi/lo planes + scaled norms.
// ---------------------------------------------------------------------------
__global__ __launch_bounds__(256) void feat_kernel(
    const float* __restrict__ X, const float* __restrict__ Y,
    const float* __restrict__ W1, const float* __restrict__ b1,
    const float* __restrict__ W2, const float* __restrict__ b2,
    const float* __restrict__ W3, const float* __restrict__ b3,
    _Float16* __restrict__ fh, _Float16* __restrict__ fl,
    float* __restrict__ ns)
{
    __shared__ float wl[2048 + 1024 + 1024 + 32 + 32 + 32];
    float* w1l = wl;
    float* w2l = w1l + 2048;
    float* w3l = w2l + 1024;
    float* b1l = w3l + 1024;
    float* b2l = b1l + 32;
    float* b3l = b2l + 32;

    const int tid = threadIdx.x;
    for (int i = tid; i < 2048; i += 256) w1l[i] = W1[i];
    for (int i = tid; i < 1024; i += 256) w2l[i] = W2[i];
    for (int i = tid; i < 1024; i += 256) w3l[i] = W3[i];
    if (tid < 32) { b1l[tid] = b1[tid]; b2l[tid] = b2[tid]; b3l[tid] = b3[tid]; }
    __syncthreads();

    const int row = blockIdx.x * 256 + tid;
    const float* src = (row < N_ROWS) ? (X + (size_t)row * D_IN)
                                      : (Y + (size_t)(row - N_ROWS) * D_IN);

    float x[D_IN];
    {
        const float4* s4 = (const float4*)src;
        #pragma unroll
        for (int c = 0; c < 16; ++c) {
            float4 v = s4[c];
            x[4*c+0] = v.x; x[4*c+1] = v.y; x[4*c+2] = v.z; x[4*c+3] = v.w;
        }
    }

    float h1[H_DIM];
    {
        const float4* wq = (const float4*)w1l;
        const float4* bq = (const float4*)b1l;
        for (int q = 0; q < 8; ++q) {
            float4 a = bq[q];
            #pragma unroll 8
            for (int k = 0; k < 64; ++k) {
                float4 w = wq[k*8 + q];
                a.x = fmaf(x[k], w.x, a.x);
                a.y = fmaf(x[k], w.y, a.y);
                a.z = fmaf(x[k], w.z, a.z);
                a.w = fmaf(x[k], w.w, a.w);
            }
            h1[4*q+0] = fmaxf(a.x, 0.f); h1[4*q+1] = fmaxf(a.y, 0.f);
            h1[4*q+2] = fmaxf(a.z, 0.f); h1[4*q+3] = fmaxf(a.w, 0.f);
        }
    }

    float h2[H_DIM];
    {
        const float4* wq = (const float4*)w2l;
        const float4* bq = (const float4*)b2l;
        for (int q = 0; q < 8; ++q) {
            float4 a = bq[q];
            #pragma unroll 8
            for (int k = 0; k < 32; ++k) {
                float4 w = wq[k*8 + q];
                a.x = fmaf(h1[k], w.x, a.x);
                a.y = fmaf(h1[k], w.y, a.y);
                a.z = fmaf(h1[k], w.z, a.z);
                a.w = fmaf(h1[k], w.w, a.w);
            }
            h2[4*q+0] = fmaxf(a.x, 0.f); h2[4*q+1] = fmaxf(a.y, 0.f);
            h2[4*q+2] = fmaxf(a.z, 0.f); h2[4*q+3] = fmaxf(a.w, 0.f);
        }
    }

    float h3[H_DIM];
    {
        const float4* wq = (const float4*)w3l;
        const float4* bq = (const float4*)b3l;
        for (int q = 0; q < 8; ++q) {
            float4 a = bq[q];
            #pragma unroll 8
            for (int k = 0; k < 32; ++k) {
                float4 w = wq[k*8 + q];
                a.x = fmaf(h2[k], w.x, a.x);
                a.y = fmaf(h2[k], w.y, a.y);
                a.z = fmaf(h2[k], w.z, a.z);
                a.w = fmaf(h2[k], w.w, a.w);
            }
            h3[4*q+0] = fmaxf(a.x, 0.f); h3[4*q+1] = fmaxf(a.y, 0.f);
            h3[4*q+2] = fmaxf(a.z, 0.f); h3[4*q+3] = fmaxf(a.w, 0.f);
        }
    }

    float nrm = 0.f;
    const float scale = (row < N_ROWS) ? LOG2E : 1.0f;
    union { _Float16 h[32]; uint4 q[4]; } hh, ll;
    #pragma unroll
    for (int c = 0; c < 32; ++c) {
        float v = h3[c];
        nrm = fmaf(v, v, nrm);
        float sv = v * scale;
        _Float16 hi = (_Float16)sv;
        hh.h[c] = hi;
        ll.h[c] = (_Float16)(sv - (float)hi);
    }
    uint4* ph = (uint4*)(fh + (size_t)row * H_DIM);
    uint4* pl = (uint4*)(fl + (size_t)row * H_DIM);
    #pragma unroll
    for (int c = 0; c < 4; ++c) { ph[c] = hh.q[c]; pl[c] = ll.q[c]; }
    ns[row] = NHALF_SC * nrm;
}

// ---------------------------------------------------------------------------
// Kernel 2: build transposed, hi/lo-split, extended Y_target:
// Ytt[t][c], t=0..7: Yt[c][t]; t=8: 1.0 (wsum column); t=9..15: 0.
// ---------------------------------------------------------------------------
__global__ __launch_bounds__(256) void ytt_kernel(
    const float* __restrict__ Yt,
    _Float16* __restrict__ yth, _Float16* __restrict__ ytl)
{
    const int c = blockIdx.x * 256 + threadIdx.x;
    #pragma unroll
    for (int t = 0; t < 16; ++t) {
        float v = (t < T_OUT) ? Yt[(size_t)c * T_OUT + t] : (t == 8 ? 1.0f : 0.0f);
        _Float16 hi = (_Float16)v;
        yth[(size_t)t * M_ROWS + c] = hi;
        ytl[(size_t)t * M_ROWS + c] = (_Float16)(v - (float)hi);
    }
}

// ---------------------------------------------------------------------------
// Kernel 3: fused MFMA pair kernel. Block = 4 waves; wave owns a 32-row
// stripe; block covers 128 rows x one 512-col j-slice. Per 32x32 j-tile:
// QK^T via 6x mfma_32x32x16_f16 (hi/lo), exp2 epilogue, P packed {hi,lo}
// per dword into wave-private LDS, read back in A-layout, PV via
// 6x mfma_16x16x32_f16 against transposed hi/lo Y_target (+ones col).
// ---------------------------------------------------------------------------
__global__ __launch_bounds__(256, 4) void pair_kernel(
    const _Float16* __restrict__ fh, const _Float16* __restrict__ fl,
    const float* __restrict__ ns,
    const _Float16* __restrict__ yth, const _Float16* __restrict__ ytl,
    float* __restrict__ pout, float* __restrict__ psum)
{
    __shared__ unsigned int plds[4][32 * PSTRIDE];

    const int tid  = threadIdx.x;
    const int wave = tid >> 6;
    const int lane = tid & 63;
    const int n    = lane & 31;    // A-row / B-col index within tile
    const int h    = lane >> 5;    // k-half selector
    const int m16  = lane & 15;    // PV m-row / t-col
    const int quad = lane >> 4;    // PV k-quad

    const int rowbase = blockIdx.x * 128 + wave * 32;
    const int s       = blockIdx.y;
    const int jstart  = s * JSLICE;

    unsigned int* pw = plds[wave];

    // Q fragments (A layout, K=32 in 2 chunks), hi and lo planes.
    const _Float16* qp = fh + (size_t)(rowbase + n) * H_DIM + h * 8;
    const _Float16* qpl = fl + (size_t)(rowbase + n) * H_DIM + h * 8;
    half8 qh0 = ld_h8(qp);
    half8 qh1 = ld_h8(qp + 16);
    half8 ql0 = ld_h8(qpl);
    half8 ql1 = ld_h8(qpl + 16);

    // Per-C-reg scaled row norms: row(reg) = (reg&3) + 8*(reg>>2) + 4*h
    float qv[16];
    #pragma unroll
    for (int r = 0; r < 16; ++r) {
        int rr = (r & 3) + 8 * (r >> 2) + 4 * h;
        qv[r] = ns[rowbase + rr];
    }

    f32x4 pv0 = {}; f32x4 pv1 = {};

    for (int jt = 0; jt < NTILES; ++jt) {
        const int jbase = jstart + jt * JTILE;

        // K-side B fragments (hi/lo)
        const _Float16* kp  = fh + (size_t)(N_ROWS + jbase + n) * H_DIM + h * 8;
        const _Float16* kpl = fl + (size_t)(N_ROWS + jbase + n) * H_DIM + h * 8;
        half8 kh0 = ld_h8(kp);
        half8 kh1 = ld_h8(kp + 16);
        half8 kl0 = ld_h8(kpl);
        half8 kl1 = ld_h8(kpl + 16);
        const float ck = ns[N_ROWS + jbase + n];

        // Ytt B fragments for PV (K=32 per tile)
        half8 yh = ld_h8(yth + (size_t)m16 * M_ROWS + jbase + quad * 8);
        half8 yl = ld_h8(ytl + (size_t)m16 * M_ROWS + jbase + quad * 8);

        // S = Qhi.Khi + Qhi.Klo + Qlo.Khi   (log2e * dot folded in)
        f32x16 acc = {};
        acc = __builtin_amdgcn_mfma_f32_32x32x16_f16(qh0, kh0, acc, 0, 0, 0);
        acc = __builtin_amdgcn_mfma_f32_32x32x16_f16(qh1, kh1, acc, 0, 0, 0);
        acc = __builtin_amdgcn_mfma_f32_32x32x16_f16(qh0, kl0, acc, 0, 0, 0);
        acc = __builtin_amdgcn_mfma_f32_32x32x16_f16(qh1, kl1, acc, 0, 0, 0);
        acc = __builtin_amdgcn_mfma_f32_32x32x16_f16(ql0, kh0, acc, 0, 0, 0);
        acc = __builtin_amdgcn_mfma_f32_32x32x16_f16(ql1, kh1, acc, 0, 0, 0);

        // Epilogue: w = 2^min(acc + qv + ck, 0); split hi/lo fp16; pack into
        // one dword {hi,lo}; store to wave-private LDS at [row][col].
        #pragma unroll
        for (int r = 0; r < 16; ++r) {
            float t = fminf(acc[r] + (qv[r] + ck), 0.0f);
            float w = __builtin_amdgcn_exp2f(t);
            fp16x2 u = __builtin_amdgcn_cvt_pkrtz(w, w);
            float back = (float)u[0];
            fp16x2 d = __builtin_amdgcn_cvt_pkrtz(w, w - back);
            int rr = (r & 3) + 8 * (r >> 2) + 4 * h;
            pw[rr * PSTRIDE + n] = __builtin_bit_cast(unsigned int, d);
        }

        // Read P back in A-layout for the two 16-row halves; extract hi/lo
        // planes with v_perm.
        #pragma unroll
        for (int H = 0; H < 2; ++H) {
            const unsigned int* rp = pw + (H * 16 + m16) * PSTRIDE + quad * 8;
            uint2 e0 = *(const uint2*)(rp + 0);
            uint2 e1 = *(const uint2*)(rp + 2);
            uint2 e2 = *(const uint2*)(rp + 4);
            uint2 e3 = *(const uint2*)(rp + 6);
            union { unsigned int u[4]; half8 v; } ahi, alo;
            ahi.u[0] = __builtin_amdgcn_perm(e0.y, e0.x, 0x05040100u);
            ahi.u[1] = __builtin_amdgcn_perm(e1.y, e1.x, 0x05040100u);
            ahi.u[2] = __builtin_amdgcn_perm(e2.y, e2.x, 0x05040100u);
            ahi.u[3] = __builtin_amdgcn_perm(e3.y, e3.x, 0x05040100u);
            alo.u[0] = __builtin_amdgcn_perm(e0.y, e0.x, 0x07060302u);
            alo.u[1] = __builtin_amdgcn_perm(e1.y, e1.x, 0x07060302u);
            alo.u[2] = __builtin_amdgcn_perm(e2.y, e2.x, 0x07060302u);
            alo.u[3] = __builtin_amdgcn_perm(e3.y, e3.x, 0x07060302u);
            if (H == 0) {
                pv0 = __builtin_amdgcn_mfma_f32_16x16x32_f16(ahi.v, yh, pv0, 0, 0, 0);
                pv0 = __builtin_amdgcn_mfma_f32_16x16x32_f16(alo.v, yh, pv0, 0, 0, 0);
                pv0 = __builtin_amdgcn_mfma_f32_16x16x32_f16(ahi.v, yl, pv0, 0, 0, 0);
            } else {
                pv1 = __builtin_amdgcn_mfma_f32_16x16x32_f16(ahi.v, yh, pv1, 0, 0, 0);
                pv1 = __builtin_amdgcn_mfma_f32_16x16x32_f16(alo.v, yh, pv1, 0, 0, 0);
                pv1 = __builtin_amdgcn_mfma_f32_16x16x32_f16(ahi.v, yl, pv1, 0, 0, 0);
            }
        }
    }

    // Write partials. PV C layout: t = lane&15, row = quad*4 + reg (+16*H).
    const int t = m16;
    if (t <= 8) {
        #pragma unroll
        for (int H = 0; H < 2; ++H) {
            #pragma unroll
            for (int r = 0; r < 4; ++r) {
                int row = rowbase + H * 16 + quad * 4 + r;
                float v = H ? pv1[r] : pv0[r];
                if (t < 8)
                    pout[((size_t)s * N_ROWS + row) * T_OUT + t] = v;
                else
                    psum[(size_t)s * N_ROWS + row] = v;
            }
        }
    }
}

// ---------------------------------------------------------------------------
// Kernel 4: reduce partials across NSPLIT j-slices and normalize.
// ---------------------------------------------------------------------------
__global__ __launch_bounds__(256) void reduce_kernel(
    const float* __restrict__ pout, const float* __restrict__ psum,
    float* __restrict__ out)
{
    const int id = blockIdx.x * 256 + threadIdx.x;   // 0..65535
    const int i = id >> 3;
    float sv = 0.f, sw = 0.f;
    #pragma unroll
    for (int s = 0; s < NSPLIT; ++s) {
        sv += pout[(size_t)s * N_ROWS * T_OUT + id];
        sw += psum[(size_t)s * N_ROWS + i];
    }
    out[id] = sv / sw;
}

// ---------------------------------------------------------------------------
extern "C" void kernel_launch(void* const* d_in, const int* in_sizes, int n_in,
                              void* d_out, int out_size, void* d_ws, size_t ws_size,
                              hipStream_t stream)
{
    const float* X  = (const float*)d_in[0];
    const float* Y  = (const float*)d_in[1];
    const float* Yt = (const float*)d_in[2];
    const float* W1 = (const float*)d_in[3];
    const float* b1 = (const float*)d_in[4];
    const float* W2 = (const float*)d_in[5];
    const float* b2 = (const float*)d_in[6];
    const float* W3 = (const float*)d_in[7];
    const float* b3 = (const float*)d_in[8];
    float* out = (float*)d_out;

    char* ws = (char*)d_ws;
    const size_t n_feat = (size_t)(N_ROWS + M_ROWS) * H_DIM;   // 524288
    _Float16* fh  = (_Float16*)ws;                 ws += n_feat * 2;            // 1 MB
    _Float16* fl  = (_Float16*)ws;                 ws += n_feat * 2;            // 1 MB
    float*    ns  = (float*)ws;                    ws += (N_ROWS + M_ROWS) * 4; // 64 KB
    _Float16* yth = (_Float16*)ws;                 ws += 16 * M_ROWS * 2;       // 256 KB
    _Float16* ytl = (_Float16*)ws;                 ws += 16 * M_ROWS * 2;       // 256 KB
    float*    pout = (float*)ws;                   ws += (size_t)NSPLIT * N_ROWS * T_OUT * 4; // 4 MB
    float*    psum = (float*)ws;                   // 512 KB

    feat_kernel<<<(N_ROWS + M_ROWS) / 256, 256, 0, stream>>>(
        X, Y, W1, b1, W2, b2, W3, b3, fh, fl, ns);
    ytt_kernel<<<M_ROWS / 256, 256, 0, stream>>>(Yt, yth, ytl);

    dim3 grid2(N_ROWS / 128, NSPLIT);
    pair_kernel<<<grid2, 256, 0, stream>>>(fh, fl, ns, yth, ytl, pout, psum);

    reduce_kernel<<<(N_ROWS * T_OUT) / 256, 256, 0, stream>>>(pout, psum, out);
}

// Round 5
// 131.528 us; speedup vs baseline: 1.6876x; 1.0878x over previous
//
#include <hip/hip_runtime.h>
#include <hip/hip_bf16.h>
#include <cstddef>

#define N_ROWS 8192
#define M_ROWS 8192
#define D_IN   64
#define H_DIM  32
#define T_OUT  8

#define NSPLIT   16          // j-splits (blockIdx.y)
#define JSLICE   (M_ROWS / NSPLIT)   // 512 cols per block
#define JTILE    32
#define NTILES   (JSLICE / JTILE)    // 16 j-tiles per block
#define LOG2E    1.4426950408889634f
#define NHALF_SC (-0.72134752044448169f)   // -0.5*log2(e)
#define PSTRIDE  34          // padded dword stride of packed P rows

typedef _Float16 half8  __attribute__((ext_vector_type(8)));
typedef __fp16   fp16x2 __attribute__((ext_vector_type(2)));
typedef float    f32x4  __attribute__((ext_vector_type(4)));
typedef float    f32x16 __attribute__((ext_vector_type(16)));

__device__ __forceinline__ half8 ld_h8(const _Float16* p) {
    return *(const half8*)p;
}

// ---------------------------------------------------------------------------
// Kernel 1: features. rows 0..N-1 -> MLP(X) (scaled by log2e), rows N..N+M-1
// -> MLP(Y) (unscaled). Emits fp16 hi/lo planes + scaled norms.
// 64-thread blocks, one row per thread, FULL unrolls (no dynamic local
// indexing -> no scratch spill; 46us->~6us was a scratch-stall signature).
// ---------------------------------------------------------------------------
__global__ __launch_bounds__(64) void feat_kernel(
    const float* __restrict__ X, const float* __restrict__ Y,
    const float* __restrict__ W1, const float* __restrict__ b1,
    const float* __restrict__ W2, const float* __restrict__ b2,
    const float* __restrict__ W3, const float* __restrict__ b3,
    _Float16* __restrict__ fh, _Float16* __restrict__ fl,
    float* __restrict__ ns)
{
    __shared__ float wl[2048 + 1024 + 1024 + 32 + 32 + 32];
    float* w1l = wl;
    float* w2l = w1l + 2048;
    float* w3l = w2l + 1024;
    float* b1l = w3l + 1024;
    float* b2l = b1l + 32;
    float* b3l = b2l + 32;

    const int tid = threadIdx.x;
    #pragma unroll
    for (int i = 0; i < 32; ++i) w1l[tid + 64 * i] = W1[tid + 64 * i];
    #pragma unroll
    for (int i = 0; i < 16; ++i) w2l[tid + 64 * i] = W2[tid + 64 * i];
    #pragma unroll
    for (int i = 0; i < 16; ++i) w3l[tid + 64 * i] = W3[tid + 64 * i];
    if (tid < 32) { b1l[tid] = b1[tid]; b2l[tid] = b2[tid]; b3l[tid] = b3[tid]; }
    __syncthreads();

    const int row = blockIdx.x * 64 + tid;
    const float* src = (row < N_ROWS) ? (X + (size_t)row * D_IN)
                                      : (Y + (size_t)(row - N_ROWS) * D_IN);

    float x[D_IN];
    {
        const float4* s4 = (const float4*)src;
        #pragma unroll
        for (int c = 0; c < 16; ++c) {
            float4 v = s4[c];
            x[4*c+0] = v.x; x[4*c+1] = v.y; x[4*c+2] = v.z; x[4*c+3] = v.w;
        }
    }

    // Layer 1: h1 = relu(x @ W1 + b1), W1 is [64][32]
    float h1[H_DIM];
    {
        const float4* wq = (const float4*)w1l;
        const float4* bq = (const float4*)b1l;
        #pragma unroll
        for (int q = 0; q < 8; ++q) {
            float4 a = bq[q];
            #pragma unroll
            for (int k = 0; k < 64; ++k) {
                float4 w = wq[k*8 + q];
                a.x = fmaf(x[k], w.x, a.x);
                a.y = fmaf(x[k], w.y, a.y);
                a.z = fmaf(x[k], w.z, a.z);
                a.w = fmaf(x[k], w.w, a.w);
            }
            h1[4*q+0] = fmaxf(a.x, 0.f); h1[4*q+1] = fmaxf(a.y, 0.f);
            h1[4*q+2] = fmaxf(a.z, 0.f); h1[4*q+3] = fmaxf(a.w, 0.f);
        }
    }

    // Layer 2
    float h2[H_DIM];
    {
        const float4* wq = (const float4*)w2l;
        const float4* bq = (const float4*)b2l;
        #pragma unroll
        for (int q = 0; q < 8; ++q) {
            float4 a = bq[q];
            #pragma unroll
            for (int k = 0; k < 32; ++k) {
                float4 w = wq[k*8 + q];
                a.x = fmaf(h1[k], w.x, a.x);
                a.y = fmaf(h1[k], w.y, a.y);
                a.z = fmaf(h1[k], w.z, a.z);
                a.w = fmaf(h1[k], w.w, a.w);
            }
            h2[4*q+0] = fmaxf(a.x, 0.f); h2[4*q+1] = fmaxf(a.y, 0.f);
            h2[4*q+2] = fmaxf(a.z, 0.f); h2[4*q+3] = fmaxf(a.w, 0.f);
        }
    }

    // Layer 3
    float h3[H_DIM];
    {
        const float4* wq = (const float4*)w3l;
        const float4* bq = (const float4*)b3l;
        #pragma unroll
        for (int q = 0; q < 8; ++q) {
            float4 a = bq[q];
            #pragma unroll
            for (int k = 0; k < 32; ++k) {
                float4 w = wq[k*8 + q];
                a.x = fmaf(h2[k], w.x, a.x);
                a.y = fmaf(h2[k], w.y, a.y);
                a.z = fmaf(h2[k], w.z, a.z);
                a.w = fmaf(h2[k], w.w, a.w);
            }
            h3[4*q+0] = fmaxf(a.x, 0.f); h3[4*q+1] = fmaxf(a.y, 0.f);
            h3[4*q+2] = fmaxf(a.z, 0.f); h3[4*q+3] = fmaxf(a.w, 0.f);
        }
    }

    float nrm = 0.f;
    const float scale = (row < N_ROWS) ? LOG2E : 1.0f;
    union { _Float16 h[32]; uint4 q[4]; } hh, ll;
    #pragma unroll
    for (int c = 0; c < 32; ++c) {
        float v = h3[c];
        nrm = fmaf(v, v, nrm);
        float sv = v * scale;
        _Float16 hi = (_Float16)sv;
        hh.h[c] = hi;
        ll.h[c] = (_Float16)(sv - (float)hi);
    }
    uint4* ph = (uint4*)(fh + (size_t)row * H_DIM);
    uint4* pl = (uint4*)(fl + (size_t)row * H_DIM);
    #pragma unroll
    for (int c = 0; c < 4; ++c) { ph[c] = hh.q[c]; pl[c] = ll.q[c]; }
    ns[row] = NHALF_SC * nrm;
}

// ---------------------------------------------------------------------------
// Kernel 2: build transposed, hi/lo-split, extended Y_target:
// Ytt[t][c], t=0..7: Yt[c][t]; t=8: 1.0 (wsum column); t=9..15: 0.
// ---------------------------------------------------------------------------
__global__ __launch_bounds__(256) void ytt_kernel(
    const float* __restrict__ Yt,
    _Float16* __restrict__ yth, _Float16* __restrict__ ytl)
{
    const int c = blockIdx.x * 256 + threadIdx.x;
    #pragma unroll
    for (int t = 0; t < 16; ++t) {
        float v = (t < T_OUT) ? Yt[(size_t)c * T_OUT + t] : (t == 8 ? 1.0f : 0.0f);
        _Float16 hi = (_Float16)v;
        yth[(size_t)t * M_ROWS + c] = hi;
        ytl[(size_t)t * M_ROWS + c] = (_Float16)(v - (float)hi);
    }
}

// ---------------------------------------------------------------------------
// Kernel 3: fused MFMA pair kernel. Block = 4 waves; wave owns a 32-row
// stripe; block covers 128 rows x one 512-col j-slice. Per 32x32 j-tile:
// QK^T via 6x mfma_32x32x16_f16 (hi/lo), exp2 epilogue, P packed {hi,lo}
// per dword into wave-private LDS, read back in A-layout, PV via
// 6x mfma_16x16x32_f16 against transposed hi/lo Y_target (+ones col).
// ---------------------------------------------------------------------------
__global__ __launch_bounds__(256, 4) void pair_kernel(
    const _Float16* __restrict__ fh, const _Float16* __restrict__ fl,
    const float* __restrict__ ns,
    const _Float16* __restrict__ yth, const _Float16* __restrict__ ytl,
    float* __restrict__ pout, float* __restrict__ psum)
{
    __shared__ unsigned int plds[4][32 * PSTRIDE];

    const int tid  = threadIdx.x;
    const int wave = tid >> 6;
    const int lane = tid & 63;
    const int n    = lane & 31;    // A-row / B-col index within tile
    const int h    = lane >> 5;    // k-half selector
    const int m16  = lane & 15;    // PV m-row / t-col
    const int quad = lane >> 4;    // PV k-quad

    const int rowbase = blockIdx.x * 128 + wave * 32;
    const int s       = blockIdx.y;
    const int jstart  = s * JSLICE;

    unsigned int* pw = plds[wave];

    // Q fragments (A layout, K=32 in 2 chunks), hi and lo planes.
    const _Float16* qp = fh + (size_t)(rowbase + n) * H_DIM + h * 8;
    const _Float16* qpl = fl + (size_t)(rowbase + n) * H_DIM + h * 8;
    half8 qh0 = ld_h8(qp);
    half8 qh1 = ld_h8(qp + 16);
    half8 ql0 = ld_h8(qpl);
    half8 ql1 = ld_h8(qpl + 16);

    // Per-C-reg scaled row norms: row(reg) = (reg&3) + 8*(reg>>2) + 4*h
    float qv[16];
    #pragma unroll
    for (int r = 0; r < 16; ++r) {
        int rr = (r & 3) + 8 * (r >> 2) + 4 * h;
        qv[r] = ns[rowbase + rr];
    }

    f32x4 pv0 = {}; f32x4 pv1 = {};

    for (int jt = 0; jt < NTILES; ++jt) {
        const int jbase = jstart + jt * JTILE;

        // K-side B fragments (hi/lo)
        const _Float16* kp  = fh + (size_t)(N_ROWS + jbase + n) * H_DIM + h * 8;
        const _Float16* kpl = fl + (size_t)(N_ROWS + jbase + n) * H_DIM + h * 8;
        half8 kh0 = ld_h8(kp);
        half8 kh1 = ld_h8(kp + 16);
        half8 kl0 = ld_h8(kpl);
        half8 kl1 = ld_h8(kpl + 16);
        const float ck = ns[N_ROWS + jbase + n];

        // Ytt B fragments for PV (K=32 per tile)
        half8 yh = ld_h8(yth + (size_t)m16 * M_ROWS + jbase + quad * 8);
        half8 yl = ld_h8(ytl + (size_t)m16 * M_ROWS + jbase + quad * 8);

        // S = Qhi.Khi + Qhi.Klo + Qlo.Khi   (log2e * dot folded in)
        f32x16 acc = {};
        acc = __builtin_amdgcn_mfma_f32_32x32x16_f16(qh0, kh0, acc, 0, 0, 0);
        acc = __builtin_amdgcn_mfma_f32_32x32x16_f16(qh1, kh1, acc, 0, 0, 0);
        acc = __builtin_amdgcn_mfma_f32_32x32x16_f16(qh0, kl0, acc, 0, 0, 0);
        acc = __builtin_amdgcn_mfma_f32_32x32x16_f16(qh1, kl1, acc, 0, 0, 0);
        acc = __builtin_amdgcn_mfma_f32_32x32x16_f16(ql0, kh0, acc, 0, 0, 0);
        acc = __builtin_amdgcn_mfma_f32_32x32x16_f16(ql1, kh1, acc, 0, 0, 0);

        // Epilogue: w = 2^min(acc + qv + ck, 0); split hi/lo fp16; pack into
        // one dword {hi,lo}; store to wave-private LDS at [row][col].
        #pragma unroll
        for (int r = 0; r < 16; ++r) {
            float t = fminf(acc[r] + (qv[r] + ck), 0.0f);
            float w = __builtin_amdgcn_exp2f(t);
            fp16x2 u = __builtin_amdgcn_cvt_pkrtz(w, w);
            float back = (float)u[0];
            fp16x2 d = __builtin_amdgcn_cvt_pkrtz(w, w - back);
            int rr = (r & 3) + 8 * (r >> 2) + 4 * h;
            pw[rr * PSTRIDE + n] = __builtin_bit_cast(unsigned int, d);
        }

        // Read P back in A-layout for the two 16-row halves; extract hi/lo
        // planes with v_perm.
        #pragma unroll
        for (int H = 0; H < 2; ++H) {
            const unsigned int* rp = pw + (H * 16 + m16) * PSTRIDE + quad * 8;
            uint2 e0 = *(const uint2*)(rp + 0);
            uint2 e1 = *(const uint2*)(rp + 2);
            uint2 e2 = *(const uint2*)(rp + 4);
            uint2 e3 = *(const uint2*)(rp + 6);
            union { unsigned int u[4]; half8 v; } ahi, alo;
            ahi.u[0] = __builtin_amdgcn_perm(e0.y, e0.x, 0x05040100u);
            ahi.u[1] = __builtin_amdgcn_perm(e1.y, e1.x, 0x05040100u);
            ahi.u[2] = __builtin_amdgcn_perm(e2.y, e2.x, 0x05040100u);
            ahi.u[3] = __builtin_amdgcn_perm(e3.y, e3.x, 0x05040100u);
            alo.u[0] = __builtin_amdgcn_perm(e0.y, e0.x, 0x07060302u);
            alo.u[1] = __builtin_amdgcn_perm(e1.y, e1.x, 0x07060302u);
            alo.u[2] = __builtin_amdgcn_perm(e2.y, e2.x, 0x07060302u);
            alo.u[3] = __builtin_amdgcn_perm(e3.y, e3.x, 0x07060302u);
            if (H == 0) {
                pv0 = __builtin_amdgcn_mfma_f32_16x16x32_f16(ahi.v, yh, pv0, 0, 0, 0);
                pv0 = __builtin_amdgcn_mfma_f32_16x16x32_f16(alo.v, yh, pv0, 0, 0, 0);
                pv0 = __builtin_amdgcn_mfma_f32_16x16x32_f16(ahi.v, yl, pv0, 0, 0, 0);
            } else {
                pv1 = __builtin_amdgcn_mfma_f32_16x16x32_f16(ahi.v, yh, pv1, 0, 0, 0);
                pv1 = __builtin_amdgcn_mfma_f32_16x16x32_f16(alo.v, yh, pv1, 0, 0, 0);
                pv1 = __builtin_amdgcn_mfma_f32_16x16x32_f16(ahi.v, yl, pv1, 0, 0, 0);
            }
        }
    }

    // Write partials. PV C layout: t = lane&15, row = quad*4 + reg (+16*H).
    const int t = m16;
    if (t <= 8) {
        #pragma unroll
        for (int H = 0; H < 2; ++H) {
            #pragma unroll
            for (int r = 0; r < 4; ++r) {
                int row = rowbase + H * 16 + quad * 4 + r;
                float v = H ? pv1[r] : pv0[r];
                if (t < 8)
                    pout[((size_t)s * N_ROWS + row) * T_OUT + t] = v;
                else
                    psum[(size_t)s * N_ROWS + row] = v;
            }
        }
    }
}

// ---------------------------------------------------------------------------
// Kernel 4: reduce partials across NSPLIT j-slices and normalize.
// ---------------------------------------------------------------------------
__global__ __launch_bounds__(256) void reduce_kernel(
    const float* __restrict__ pout, const float* __restrict__ psum,
    float* __restrict__ out)
{
    const int id = blockIdx.x * 256 + threadIdx.x;   // 0..65535
    const int i = id >> 3;
    float sv = 0.f, sw = 0.f;
    #pragma unroll
    for (int s = 0; s < NSPLIT; ++s) {
        sv += pout[(size_t)s * N_ROWS * T_OUT + id];
        sw += psum[(size_t)s * N_ROWS + i];
    }
    out[id] = sv / sw;
}

// ---------------------------------------------------------------------------
extern "C" void kernel_launch(void* const* d_in, const int* in_sizes, int n_in,
                              void* d_out, int out_size, void* d_ws, size_t ws_size,
                              hipStream_t stream)
{
    const float* X  = (const float*)d_in[0];
    const float* Y  = (const float*)d_in[1];
    const float* Yt = (const float*)d_in[2];
    const float* W1 = (const float*)d_in[3];
    const float* b1 = (const float*)d_in[4];
    const float* W2 = (const float*)d_in[5];
    const float* b2 = (const float*)d_in[6];
    const float* W3 = (const float*)d_in[7];
    const float* b3 = (const float*)d_in[8];
    float* out = (float*)d_out;

    char* ws = (char*)d_ws;
    const size_t n_feat = (size_t)(N_ROWS + M_ROWS) * H_DIM;   // 524288
    _Float16* fh  = (_Float16*)ws;                 ws += n_feat * 2;            // 1 MB
    _Float16* fl  = (_Float16*)ws;                 ws += n_feat * 2;            // 1 MB
    float*    ns  = (float*)ws;                    ws += (N_ROWS + M_ROWS) * 4; // 64 KB
    _Float16* yth = (_Float16*)ws;                 ws += 16 * M_ROWS * 2;       // 256 KB
    _Float16* ytl = (_Float16*)ws;                 ws += 16 * M_ROWS * 2;       // 256 KB
    float*    pout = (float*)ws;                   ws += (size_t)NSPLIT * N_ROWS * T_OUT * 4; // 4 MB
    float*    psum = (float*)ws;                   // 512 KB

    feat_kernel<<<(N_ROWS + M_ROWS) / 64, 64, 0, stream>>>(
        X, Y, W1, b1, W2, b2, W3, b3, fh, fl, ns);
    ytt_kernel<<<M_ROWS / 256, 256, 0, stream>>>(Yt, yth, ytl);

    dim3 grid2(N_ROWS / 128, NSPLIT);
    pair_kernel<<<grid2, 256, 0, stream>>>(fh, fl, ns, yth, ytl, pout, psum);

    reduce_kernel<<<(N_ROWS * T_OUT) / 256, 256, 0, stream>>>(pout, psum, out);
}

// Round 6
// 116.704 us; speedup vs baseline: 1.9020x; 1.1270x over previous
//
#include <hip/hip_runtime.h>
#include <hip/hip_bf16.h>
#include <cstddef>

#define N_ROWS 8192
#define M_ROWS 8192
#define D_IN   64
#define H_DIM  32
#define T_OUT  8

#define NSPLIT   16          // j-splits (blockIdx.y)
#define JSLICE   (M_ROWS / NSPLIT)   // 512 cols per block
#define JTILE    32
#define NTILES   (JSLICE / JTILE)    // 16 j-tiles per block
#define LOG2E    1.4426950408889634f
#define NHALF_SC (-0.72134752044448169f)   // -0.5*log2(e)
#define PSTRIDE  34          // padded dword stride of packed P rows

typedef _Float16 half8  __attribute__((ext_vector_type(8)));
typedef __fp16   fp16x2 __attribute__((ext_vector_type(2)));
typedef float    f32x4  __attribute__((ext_vector_type(4)));
typedef float    f32x16 __attribute__((ext_vector_type(16)));

__device__ __forceinline__ half8 ld_h8(const _Float16* p) {
    return *(const half8*)p;
}

// ---------------------------------------------------------------------------
// Kernel 1 (v3): features, column-split. Block = 256 threads / 4 waves,
// 32 rows per block, thread = (row = tid&31, cols = (tid>>5)*4 ..+3).
// Rationale (R5 counters): thread=row gave 1 wave/CU, VALUBusy 2.6%,
// ~1024 serial LDS loads/thread -> latency-bound 60us. Column split cuts
// LDS reads/thread 4x, doubles waves/SIMD, all reads bank-conflict-free.
// ---------------------------------------------------------------------------
__global__ __launch_bounds__(256) void feat_kernel(
    const float* __restrict__ X, const float* __restrict__ Y,
    const float* __restrict__ W1, const float* __restrict__ b1,
    const float* __restrict__ W2, const float* __restrict__ b2,
    const float* __restrict__ W3, const float* __restrict__ b3,
    _Float16* __restrict__ fh, _Float16* __restrict__ fl,
    float* __restrict__ ns)
{
    __shared__ float xs [32 * 65];   // [row][k] stride 65: banks (r+k)%32
    __shared__ float w1l[64 * 36];   // [k][col] stride 36
    __shared__ float w2l[32 * 36];
    __shared__ float w3l[32 * 36];
    __shared__ float h1t[32 * 33];   // transposed [col][row] stride 33
    __shared__ float h2t[32 * 33];
    __shared__ float psums[8 * 32];  // [colgroup][row] norm partials
    __shared__ float bl[96];

    const int tid = threadIdx.x;
    const int rowbase = blockIdx.x * 32;           // 512 blocks
    const bool isX = rowbase < N_ROWS;
    const float* src = isX ? (X + (size_t)rowbase * D_IN)
                           : (Y + (size_t)(rowbase - N_ROWS) * D_IN);

    // ---- stage X rows: 2048 floats, 8 per thread ----
    {
        const float4* g4 = (const float4*)src;
        int i0 = tid * 2;
        float4 v0 = g4[i0], v1 = g4[i0 + 1];
        int f0 = tid * 8;
        int r = f0 >> 6, c = f0 & 63;
        float* dst = xs + r * 65 + c;
        dst[0] = v0.x; dst[1] = v0.y; dst[2] = v0.z; dst[3] = v0.w;
        dst[4] = v1.x; dst[5] = v1.y; dst[6] = v1.z; dst[7] = v1.w;
    }
    // ---- stage W1: 2048 floats ----
    {
        const float4* g4 = (const float4*)W1;
        int i0 = tid * 2;
        float4 v0 = g4[i0], v1 = g4[i0 + 1];
        int f0 = tid * 8;
        int r = f0 >> 5, c = f0 & 31;              // c in {0,8,16,24}
        float* dst = w1l + r * 36 + c;
        ((float4*)dst)[0] = v0; ((float4*)dst)[1] = v1;
    }
    // ---- stage W2, W3: 1024 floats each, 1 float4 per thread ----
    {
        int f0 = tid * 4;
        int r = f0 >> 5, c = f0 & 31;              // c in {0,4,...,28}
        *(float4*)(w2l + r * 36 + c) = ((const float4*)W2)[tid];
        *(float4*)(w3l + r * 36 + c) = ((const float4*)W3)[tid];
    }
    if (tid < 32) { bl[tid] = b1[tid]; bl[32 + tid] = b2[tid]; bl[64 + tid] = b3[tid]; }
    __syncthreads();

    const int r  = tid & 31;
    const int c0 = (tid >> 5) * 4;

    // ---- layer 1: 64-k, 4 cols ----
    float4 a1 = *(const float4*)(bl + c0);
    #pragma unroll
    for (int k = 0; k < 64; ++k) {
        float xv = xs[r * 65 + k];
        float4 w = *(const float4*)(w1l + k * 36 + c0);
        a1.x = fmaf(xv, w.x, a1.x);
        a1.y = fmaf(xv, w.y, a1.y);
        a1.z = fmaf(xv, w.z, a1.z);
        a1.w = fmaf(xv, w.w, a1.w);
    }
    h1t[(c0 + 0) * 33 + r] = fmaxf(a1.x, 0.f);
    h1t[(c0 + 1) * 33 + r] = fmaxf(a1.y, 0.f);
    h1t[(c0 + 2) * 33 + r] = fmaxf(a1.z, 0.f);
    h1t[(c0 + 3) * 33 + r] = fmaxf(a1.w, 0.f);
    __syncthreads();

    // ---- layer 2 ----
    float4 a2 = *(const float4*)(bl + 32 + c0);
    #pragma unroll
    for (int k = 0; k < 32; ++k) {
        float xv = h1t[k * 33 + r];
        float4 w = *(const float4*)(w2l + k * 36 + c0);
        a2.x = fmaf(xv, w.x, a2.x);
        a2.y = fmaf(xv, w.y, a2.y);
        a2.z = fmaf(xv, w.z, a2.z);
        a2.w = fmaf(xv, w.w, a2.w);
    }
    h2t[(c0 + 0) * 33 + r] = fmaxf(a2.x, 0.f);
    h2t[(c0 + 1) * 33 + r] = fmaxf(a2.y, 0.f);
    h2t[(c0 + 2) * 33 + r] = fmaxf(a2.z, 0.f);
    h2t[(c0 + 3) * 33 + r] = fmaxf(a2.w, 0.f);
    __syncthreads();

    // ---- layer 3 (outputs stay in regs) ----
    float4 a3 = *(const float4*)(bl + 64 + c0);
    #pragma unroll
    for (int k = 0; k < 32; ++k) {
        float xv = h2t[k * 33 + r];
        float4 w = *(const float4*)(w3l + k * 36 + c0);
        a3.x = fmaf(xv, w.x, a3.x);
        a3.y = fmaf(xv, w.y, a3.y);
        a3.z = fmaf(xv, w.z, a3.z);
        a3.w = fmaf(xv, w.w, a3.w);
    }
    float v0 = fmaxf(a3.x, 0.f), v1 = fmaxf(a3.y, 0.f);
    float v2 = fmaxf(a3.z, 0.f), v3 = fmaxf(a3.w, 0.f);

    // ---- norm partials: 8 colgroups per row ----
    float part = v0 * v0 + v1 * v1 + v2 * v2 + v3 * v3;
    psums[(tid >> 5) * 32 + r] = part;

    // ---- hi/lo split + global write (8 B per plane per thread) ----
    const float scale = isX ? LOG2E : 1.0f;
    union { _Float16 h[4]; uint2 u; } hh, ll;
    float sv0 = v0 * scale, sv1 = v1 * scale, sv2 = v2 * scale, sv3 = v3 * scale;
    hh.h[0] = (_Float16)sv0; hh.h[1] = (_Float16)sv1;
    hh.h[2] = (_Float16)sv2; hh.h[3] = (_Float16)sv3;
    ll.h[0] = (_Float16)(sv0 - (float)hh.h[0]);
    ll.h[1] = (_Float16)(sv1 - (float)hh.h[1]);
    ll.h[2] = (_Float16)(sv2 - (float)hh.h[2]);
    ll.h[3] = (_Float16)(sv3 - (float)hh.h[3]);
    const size_t fo = (size_t)(rowbase + r) * H_DIM + c0;
    *(uint2*)(fh + fo) = hh.u;
    *(uint2*)(fl + fo) = ll.u;

    __syncthreads();
    if (tid < 32) {
        float nrm = 0.f;
        #pragma unroll
        for (int g = 0; g < 8; ++g) nrm += psums[g * 32 + tid];
        ns[rowbase + tid] = NHALF_SC * nrm;
    }
}

// ---------------------------------------------------------------------------
// Kernel 2: build transposed, hi/lo-split, extended Y_target:
// Ytt[t][c], t=0..7: Yt[c][t]; t=8: 1.0 (wsum column); t=9..15: 0.
// ---------------------------------------------------------------------------
__global__ __launch_bounds__(256) void ytt_kernel(
    const float* __restrict__ Yt,
    _Float16* __restrict__ yth, _Float16* __restrict__ ytl)
{
    const int c = blockIdx.x * 256 + threadIdx.x;
    #pragma unroll
    for (int t = 0; t < 16; ++t) {
        float v = (t < T_OUT) ? Yt[(size_t)c * T_OUT + t] : (t == 8 ? 1.0f : 0.0f);
        _Float16 hi = (_Float16)v;
        yth[(size_t)t * M_ROWS + c] = hi;
        ytl[(size_t)t * M_ROWS + c] = (_Float16)(v - (float)hi);
    }
}

// ---------------------------------------------------------------------------
// Kernel 3: fused MFMA pair kernel. Block = 4 waves; wave owns a 32-row
// stripe; block covers 128 rows x one 512-col j-slice. Per 32x32 j-tile:
// QK^T via 6x mfma_32x32x16_f16 (hi/lo), exp2 epilogue, P packed {hi,lo}
// per dword into wave-private LDS, read back in A-layout, PV via
// 6x mfma_16x16x32_f16 against transposed hi/lo Y_target (+ones col).
// ---------------------------------------------------------------------------
__global__ __launch_bounds__(256, 4) void pair_kernel(
    const _Float16* __restrict__ fh, const _Float16* __restrict__ fl,
    const float* __restrict__ ns,
    const _Float16* __restrict__ yth, const _Float16* __restrict__ ytl,
    float* __restrict__ pout, float* __restrict__ psum)
{
    __shared__ unsigned int plds[4][32 * PSTRIDE];

    const int tid  = threadIdx.x;
    const int wave = tid >> 6;
    const int lane = tid & 63;
    const int n    = lane & 31;    // A-row / B-col index within tile
    const int h    = lane >> 5;    // k-half selector
    const int m16  = lane & 15;    // PV m-row / t-col
    const int quad = lane >> 4;    // PV k-quad

    const int rowbase = blockIdx.x * 128 + wave * 32;
    const int s       = blockIdx.y;
    const int jstart  = s * JSLICE;

    unsigned int* pw = plds[wave];

    // Q fragments (A layout, K=32 in 2 chunks), hi and lo planes.
    const _Float16* qp = fh + (size_t)(rowbase + n) * H_DIM + h * 8;
    const _Float16* qpl = fl + (size_t)(rowbase + n) * H_DIM + h * 8;
    half8 qh0 = ld_h8(qp);
    half8 qh1 = ld_h8(qp + 16);
    half8 ql0 = ld_h8(qpl);
    half8 ql1 = ld_h8(qpl + 16);

    // Per-C-reg scaled row norms: row(reg) = (reg&3) + 8*(reg>>2) + 4*h
    float qv[16];
    #pragma unroll
    for (int r = 0; r < 16; ++r) {
        int rr = (r & 3) + 8 * (r >> 2) + 4 * h;
        qv[r] = ns[rowbase + rr];
    }

    f32x4 pv0 = {}; f32x4 pv1 = {};

    for (int jt = 0; jt < NTILES; ++jt) {
        const int jbase = jstart + jt * JTILE;

        // K-side B fragments (hi/lo)
        const _Float16* kp  = fh + (size_t)(N_ROWS + jbase + n) * H_DIM + h * 8;
        const _Float16* kpl = fl + (size_t)(N_ROWS + jbase + n) * H_DIM + h * 8;
        half8 kh0 = ld_h8(kp);
        half8 kh1 = ld_h8(kp + 16);
        half8 kl0 = ld_h8(kpl);
        half8 kl1 = ld_h8(kpl + 16);
        const float ck = ns[N_ROWS + jbase + n];

        // Ytt B fragments for PV (K=32 per tile)
        half8 yh = ld_h8(yth + (size_t)m16 * M_ROWS + jbase + quad * 8);
        half8 yl = ld_h8(ytl + (size_t)m16 * M_ROWS + jbase + quad * 8);

        // S = Qhi.Khi + Qhi.Klo + Qlo.Khi   (log2e * dot folded in)
        f32x16 acc = {};
        acc = __builtin_amdgcn_mfma_f32_32x32x16_f16(qh0, kh0, acc, 0, 0, 0);
        acc = __builtin_amdgcn_mfma_f32_32x32x16_f16(qh1, kh1, acc, 0, 0, 0);
        acc = __builtin_amdgcn_mfma_f32_32x32x16_f16(qh0, kl0, acc, 0, 0, 0);
        acc = __builtin_amdgcn_mfma_f32_32x32x16_f16(qh1, kl1, acc, 0, 0, 0);
        acc = __builtin_amdgcn_mfma_f32_32x32x16_f16(ql0, kh0, acc, 0, 0, 0);
        acc = __builtin_amdgcn_mfma_f32_32x32x16_f16(ql1, kh1, acc, 0, 0, 0);

        // Epilogue: w = 2^min(acc + qv + ck, 0); split hi/lo fp16; pack into
        // one dword {hi,lo}; store to wave-private LDS at [row][col].
        #pragma unroll
        for (int r = 0; r < 16; ++r) {
            float t = fminf(acc[r] + (qv[r] + ck), 0.0f);
            float w = __builtin_amdgcn_exp2f(t);
            fp16x2 u = __builtin_amdgcn_cvt_pkrtz(w, w);
            float back = (float)u[0];
            fp16x2 d = __builtin_amdgcn_cvt_pkrtz(w, w - back);
            int rr = (r & 3) + 8 * (r >> 2) + 4 * h;
            pw[rr * PSTRIDE + n] = __builtin_bit_cast(unsigned int, d);
        }

        // Read P back in A-layout for the two 16-row halves; extract hi/lo
        // planes with v_perm.
        #pragma unroll
        for (int H = 0; H < 2; ++H) {
            const unsigned int* rp = pw + (H * 16 + m16) * PSTRIDE + quad * 8;
            uint2 e0 = *(const uint2*)(rp + 0);
            uint2 e1 = *(const uint2*)(rp + 2);
            uint2 e2 = *(const uint2*)(rp + 4);
            uint2 e3 = *(const uint2*)(rp + 6);
            union { unsigned int u[4]; half8 v; } ahi, alo;
            ahi.u[0] = __builtin_amdgcn_perm(e0.y, e0.x, 0x05040100u);
            ahi.u[1] = __builtin_amdgcn_perm(e1.y, e1.x, 0x05040100u);
            ahi.u[2] = __builtin_amdgcn_perm(e2.y, e2.x, 0x05040100u);
            ahi.u[3] = __builtin_amdgcn_perm(e3.y, e3.x, 0x05040100u);
            alo.u[0] = __builtin_amdgcn_perm(e0.y, e0.x, 0x07060302u);
            alo.u[1] = __builtin_amdgcn_perm(e1.y, e1.x, 0x07060302u);
            alo.u[2] = __builtin_amdgcn_perm(e2.y, e2.x, 0x07060302u);
            alo.u[3] = __builtin_amdgcn_perm(e3.y, e3.x, 0x07060302u);
            if (H == 0) {
                pv0 = __builtin_amdgcn_mfma_f32_16x16x32_f16(ahi.v, yh, pv0, 0, 0, 0);
                pv0 = __builtin_amdgcn_mfma_f32_16x16x32_f16(alo.v, yh, pv0, 0, 0, 0);
                pv0 = __builtin_amdgcn_mfma_f32_16x16x32_f16(ahi.v, yl, pv0, 0, 0, 0);
            } else {
                pv1 = __builtin_amdgcn_mfma_f32_16x16x32_f16(ahi.v, yh, pv1, 0, 0, 0);
                pv1 = __builtin_amdgcn_mfma_f32_16x16x32_f16(alo.v, yh, pv1, 0, 0, 0);
                pv1 = __builtin_amdgcn_mfma_f32_16x16x32_f16(ahi.v, yl, pv1, 0, 0, 0);
            }
        }
    }

    // Write partials. PV C layout: t = lane&15, row = quad*4 + reg (+16*H).
    const int t = m16;
    if (t <= 8) {
        #pragma unroll
        for (int H = 0; H < 2; ++H) {
            #pragma unroll
            for (int r = 0; r < 4; ++r) {
                int row = rowbase + H * 16 + quad * 4 + r;
                float v = H ? pv1[r] : pv0[r];
                if (t < 8)
                    pout[((size_t)s * N_ROWS + row) * T_OUT + t] = v;
                else
                    psum[(size_t)s * N_ROWS + row] = v;
            }
        }
    }
}

// ---------------------------------------------------------------------------
// Kernel 4: reduce partials across NSPLIT j-slices and normalize.
// ---------------------------------------------------------------------------
__global__ __launch_bounds__(256) void reduce_kernel(
    const float* __restrict__ pout, const float* __restrict__ psum,
    float* __restrict__ out)
{
    const int id = blockIdx.x * 256 + threadIdx.x;   // 0..65535
    const int i = id >> 3;
    float sv = 0.f, sw = 0.f;
    #pragma unroll
    for (int s = 0; s < NSPLIT; ++s) {
        sv += pout[(size_t)s * N_ROWS * T_OUT + id];
        sw += psum[(size_t)s * N_ROWS + i];
    }
    out[id] = sv / sw;
}

// ---------------------------------------------------------------------------
extern "C" void kernel_launch(void* const* d_in, const int* in_sizes, int n_in,
                              void* d_out, int out_size, void* d_ws, size_t ws_size,
                              hipStream_t stream)
{
    const float* X  = (const float*)d_in[0];
    const float* Y  = (const float*)d_in[1];
    const float* Yt = (const float*)d_in[2];
    const float* W1 = (const float*)d_in[3];
    const float* b1 = (const float*)d_in[4];
    const float* W2 = (const float*)d_in[5];
    const float* b2 = (const float*)d_in[6];
    const float* W3 = (const float*)d_in[7];
    const float* b3 = (const float*)d_in[8];
    float* out = (float*)d_out;

    char* ws = (char*)d_ws;
    const size_t n_feat = (size_t)(N_ROWS + M_ROWS) * H_DIM;   // 524288
    _Float16* fh  = (_Float16*)ws;                 ws += n_feat * 2;            // 1 MB
    _Float16* fl  = (_Float16*)ws;                 ws += n_feat * 2;            // 1 MB
    float*    ns  = (float*)ws;                    ws += (N_ROWS + M_ROWS) * 4; // 64 KB
    _Float16* yth = (_Float16*)ws;                 ws += 16 * M_ROWS * 2;       // 256 KB
    _Float16* ytl = (_Float16*)ws;                 ws += 16 * M_ROWS * 2;       // 256 KB
    float*    pout = (float*)ws;                   ws += (size_t)NSPLIT * N_ROWS * T_OUT * 4; // 4 MB
    float*    psum = (float*)ws;                   // 512 KB

    feat_kernel<<<(N_ROWS + M_ROWS) / 32, 256, 0, stream>>>(
        X, Y, W1, b1, W2, b2, W3, b3, fh, fl, ns);
    ytt_kernel<<<M_ROWS / 256, 256, 0, stream>>>(Yt, yth, ytl);

    dim3 grid2(N_ROWS / 128, NSPLIT);
    pair_kernel<<<grid2, 256, 0, stream>>>(fh, fl, ns, yth, ytl, pout, psum);

    reduce_kernel<<<(N_ROWS * T_OUT) / 256, 256, 0, stream>>>(pout, psum, out);
}